// Round 8
// baseline (744.673 us; speedup 1.0000x reference)
//
#include <hip/hip_runtime.h>
#include <hip/hip_bf16.h>

// MultiHeadSelfAttention: B=2, S=2048, D=1024, H=16, Dh=64, RoPE theta=1e4, causal.
// Round 8: barrier-free attention. K/V MFMA B-frags read directly from global
// (16B/lane, line-coalesced); Q A-frags pinned in VGPRs; LDS holds only the
// per-wave P C->A transpose (9.2 KB). Zero __syncthreads. qkv/out_proj unchanged.
// ws (u16): Q[b,h,s,d] | K[b,h,s,d] | Vt[b,h,d,s] | AO[b,s,h*d], 4M elems each = 32 MB.

#define D_MODEL 1024
#define NHEADS  16
#define HDIM    64
#define SEQ     2048
#define BATCH   2

typedef unsigned short u16;
typedef __bf16 bf16x8_t __attribute__((ext_vector_type(8)));
typedef float  f32x4_t  __attribute__((ext_vector_type(4)));

__device__ __forceinline__ u16 f2bf(float f) {
    union { __hip_bfloat16 h; u16 u; } cv;
    cv.h = __float2bfloat16(f);
    return cv.u;
}

__device__ __forceinline__ unsigned pk2(float x, float y) {
    union { __hip_bfloat162 h; unsigned u; } cv;
    cv.h = __float22bfloat162_rn(make_float2(x, y));   // v_cvt_pk_bf16_f32
    return cv.u;
}

__device__ __forceinline__ uint4 pack8(float4 a, float4 b) {
    uint4 u;
    u.x = pk2(a.x, a.y);
    u.y = pk2(a.z, a.w);
    u.z = pk2(b.x, b.y);
    u.w = pk2(b.z, b.w);
    return u;
}

__device__ __forceinline__ bf16x8_t frag_ld(const u16* p) {
    union { uint4 u; bf16x8_t v; } t;
    t.u = *(const uint4*)p;
    return t.v;
}

__device__ __forceinline__ bf16x8_t asfrag(uint4 u) {
    union { uint4 u; bf16x8_t v; } t;
    t.u = u;
    return t.v;
}

// ---------------------------------------------------------------------------
// QKV projection + RoPE. C = X(4096x1024) * W^T, virtual N=3072 (q|k|v).
// 128x128 tile, BK=64, 4 waves 2x2. Q output pre-scaled by 1/8 (attn fold).
// ---------------------------------------------------------------------------
__global__ __launch_bounds__(256) void qkv_rope_kernel(
    const float* __restrict__ X, const float* __restrict__ Wq,
    const float* __restrict__ Wk, const float* __restrict__ Wv,
    const int* __restrict__ pos,
    u16* __restrict__ Qo, u16* __restrict__ Ko, u16* __restrict__ Vt)
{
    __shared__ __align__(16) u16 smem[2 * 128 * 72];        // 36864 B
    u16 (*As)[72] = (u16(*)[72])smem;                       // As[m][k]
    u16 (*Bs)[72] = (u16(*)[72])(smem + 128 * 72);          // Bs[n][k]

    const int tid = threadIdx.x;
    const int m0 = blockIdx.y * 128;
    const int nv = blockIdx.x * 128;
    const int which = nv >> 10;                 // 0=q,1=k,2=v (block-uniform)
    const int nbase = nv & 1023;
    const float* __restrict__ W = (which == 0) ? Wq : (which == 1) ? Wk : Wv;

    const int w = tid >> 6, L = tid & 63, quad = L >> 4, colL = L & 15;
    const int mw = (w & 1) * 64, nw = (w >> 1) * 64;
    const int srow = tid >> 3, skc = (tid & 7) * 8;

    f32x4_t acc[4][4];
    #pragma unroll
    for (int i = 0; i < 4; ++i)
        #pragma unroll
        for (int j = 0; j < 4; ++j) acc[i][j] = (f32x4_t){0.f, 0.f, 0.f, 0.f};

    for (int k0 = 0; k0 < D_MODEL; k0 += 64) {
        uint4 ar[4], br[4];
        #pragma unroll
        for (int p2 = 0; p2 < 4; ++p2) {
            const int row = srow + 32 * p2;
            const float* xp = X + (size_t)(m0 + row) * D_MODEL + k0 + skc;
            ar[p2] = pack8(*(const float4*)xp, *(const float4*)(xp + 4));
            const float* wp = W + (size_t)(nbase + row) * D_MODEL + k0 + skc;
            br[p2] = pack8(*(const float4*)wp, *(const float4*)(wp + 4));
        }
        __syncthreads();
        #pragma unroll
        for (int p2 = 0; p2 < 4; ++p2) {
            const int row = srow + 32 * p2;
            *(uint4*)&As[row][skc] = ar[p2];
            *(uint4*)&Bs[row][skc] = br[p2];
        }
        __syncthreads();
        #pragma unroll
        for (int kb = 0; kb < 2; ++kb) {
            bf16x8_t af[4], bf[4];
            #pragma unroll
            for (int t = 0; t < 4; ++t) {
                af[t] = frag_ld(&As[mw + t * 16 + colL][kb * 32 + quad * 8]);
                bf[t] = frag_ld(&Bs[nw + t * 16 + colL][kb * 32 + quad * 8]);
            }
            #pragma unroll
            for (int mt = 0; mt < 4; ++mt)
                #pragma unroll
                for (int nt = 0; nt < 4; ++nt)
                    acc[mt][nt] = __builtin_amdgcn_mfma_f32_16x16x32_bf16(
                        af[mt], bf[nt], acc[mt][nt], 0, 0, 0);
        }
    }

    // ---- epilogue: RoPE (regs) -> LDS tile -> coalesced stores ----
    __syncthreads();                            // done with As/Bs
    u16 (*Ts)[132] = (u16(*)[132])smem;         // 128x132 u16 = 33792 B

    const float C0 = 0.14391156831212787f;      // ln(10000)/64
    if (which < 2) {
        const float oscale = (which == 0) ? 0.125f : 1.0f;   // fold 1/sqrt(64) into Q
        float invf[4], sgn[4];
        #pragma unroll
        for (int nt = 0; nt < 4; ++nt) {
            const int n = nbase + nw + nt * 16 + colL;
            const int dd = n & 63;
            invf[nt] = __expf(-(float)(dd & 62) * C0);
            sgn[nt] = (dd & 1) ? 1.0f : -1.0f;
        }
        #pragma unroll
        for (int mt = 0; mt < 4; ++mt) {
            #pragma unroll
            for (int r = 0; r < 4; ++r) {
                const int ml = mw + mt * 16 + quad * 4 + r;
                const int ss = (m0 + ml) & 2047;
                const float p = (float)pos[ss];
                #pragma unroll
                for (int nt = 0; nt < 4; ++nt) {
                    const float v = acc[mt][nt][r];
                    const float partner = __shfl_xor(v, 1);
                    float sn, cs;
                    __sincosf(p * invf[nt], &sn, &cs);   // native, no libcall scratch
                    Ts[ml][nw + nt * 16 + colL] =
                        f2bf((v * cs + sgn[nt] * sn * partner) * oscale);
                }
            }
        }
    } else {
        #pragma unroll
        for (int mt = 0; mt < 4; ++mt)
            #pragma unroll
            for (int nt = 0; nt < 4; ++nt)
                #pragma unroll
                for (int r = 0; r < 4; ++r)
                    Ts[nw + nt * 16 + colL][mw + mt * 16 + quad * 4 + r] = f2bf(acc[mt][nt][r]);
    }
    __syncthreads();

    const int rr0 = tid >> 4;                   // 0..15
    const int cc8 = (tid & 15) * 8;             // 0..120, 8-u16 chunks
    if (which < 2) {
        u16* __restrict__ dst = (which == 0) ? Qo : Ko;
        #pragma unroll
        for (int it = 0; it < 8; ++it) {
            const int ml = rr0 + it * 16;
            const int m = m0 + ml, bb = m >> 11, ss = m & 2047;
            const int n = nbase + cc8, h = n >> 6, d = n & 63;
            *(uint4*)&dst[((size_t)(bb * NHEADS + h) * SEQ + ss) * HDIM + d] =
                *(const uint4*)&Ts[ml][cc8];
        }
    } else {
        const int bb = m0 >> 11, ss0 = (m0 & 2047) + cc8;
        #pragma unroll
        for (int it = 0; it < 8; ++it) {
            const int nl = rr0 + it * 16;
            const int n = nbase + nl, h = n >> 6, d = n & 63;
            *(uint4*)&Vt[((size_t)(bb * NHEADS + h) * HDIM + d) * SEQ + ss0] =
                *(const uint4*)&Ts[nl][cc8];
        }
    }
}

// ---------------------------------------------------------------------------
// Flash attention, causal, MFMA, max-free softmax, BARRIER-FREE.
// Wave = 16 q-rows (A-frags in VGPRs). K/V B-frags read straight from global
// (16B/lane coalesced). LDS: per-wave P transpose only. Block = 4 indep waves
// of one 64-row q-tile (L1 K/V sharing). Grid LPT: long q-tiles first.
// ---------------------------------------------------------------------------
__global__ __launch_bounds__(256) void attn_kernel(
    const u16* __restrict__ Q, const u16* __restrict__ K,
    const u16* __restrict__ Vt, u16* __restrict__ AO)
{
    __shared__ __align__(16) u16 Ps[4][16][72];   // per-wave [q_local][key]

    const int tid = threadIdx.x;
    const int qt = 31 - (int)blockIdx.x;          // LPT: longest first
    const int hh = blockIdx.y, bb = blockIdx.z;
    const size_t bh = ((size_t)bb * NHEADS + hh) * (SEQ * HDIM);

    const int w = tid >> 6, L = tid & 63, quad = L >> 4, colL = L & 15;
    const int qw0 = qt * 64 + 16 * w;             // wave's first q row
    const int nkt = qt + 1;

    // Q A-frags pinned in registers (pre-scaled by 1/8 in qkv)
    const u16* qrow = Q + bh + (size_t)(qw0 + colL) * HDIM + quad * 8;
    const bf16x8_t aq0 = frag_ld(qrow);
    const bf16x8_t aq1 = frag_ld(qrow + 32);

    // lane base pointers for direct B-frag loads
    const u16* kbase = K + bh + (size_t)colL * HDIM + quad * 8;   // +nt*16*HDIM +kb*32 +kt*64*HDIM
    const u16* vbase = Vt + bh + (size_t)colL * SEQ + quad * 8;   // +dt*16*SEQ  +kb*32 +kt*64

    float lsum[4] = {0.f, 0.f, 0.f, 0.f};
    f32x4_t O[4];
    #pragma unroll
    for (int dt = 0; dt < 4; ++dt) O[dt] = (f32x4_t){0.f, 0.f, 0.f, 0.f};

    // preload K frags for kt=0
    uint4 kf[8];
    #pragma unroll
    for (int nt = 0; nt < 4; ++nt) {
        kf[nt * 2 + 0] = *(const uint4*)(kbase + nt * 16 * HDIM);
        kf[nt * 2 + 1] = *(const uint4*)(kbase + nt * 16 * HDIM + 32);
    }

    for (int kt = 0; kt < nkt; ++kt) {
        const int k0 = kt * 64;

        // V frags for this tile (latency covered by QK + softmax)
        uint4 vf[8];
        #pragma unroll
        for (int dt = 0; dt < 4; ++dt) {
            const u16* vp = vbase + (size_t)dt * 16 * SEQ + k0;
            vf[dt * 2 + 0] = *(const uint4*)vp;
            vf[dt * 2 + 1] = *(const uint4*)(vp + 32);
        }

        const int ntmax = min(3, (qw0 + 15 - k0) >> 4);   // causal nt pruning (>=0)

        f32x4_t S[4];
        #pragma unroll
        for (int nt = 0; nt < 4; ++nt) S[nt] = (f32x4_t){0.f, 0.f, 0.f, 0.f};
        for (int nt = 0; nt <= ntmax; ++nt) {
            S[nt] = __builtin_amdgcn_mfma_f32_16x16x32_bf16(aq0, asfrag(kf[nt * 2 + 0]), S[nt], 0, 0, 0);
            S[nt] = __builtin_amdgcn_mfma_f32_16x16x32_bf16(aq1, asfrag(kf[nt * 2 + 1]), S[nt], 0, 0, 0);
        }

        // max-free softmax: p = exp(s); masked/pruned -> 0
        #pragma unroll
        for (int r = 0; r < 4; ++r) {
            const int qa = qw0 + quad * 4 + r;
            #pragma unroll
            for (int nt = 0; nt < 4; ++nt) {
                float pv = 0.0f;
                if (nt <= ntmax) {
                    const int key = k0 + nt * 16 + colL;
                    pv = (key <= qa) ? __expf(S[nt][r]) : 0.0f;
                }
                lsum[r] += pv;
                Ps[w][quad * 4 + r][nt * 16 + colL] = f2bf(pv);
            }
        }

        // prefetch K frags for next tile (covered by PV + next-QK issue)
        if (kt + 1 < nkt) {
            const u16* kn = kbase + (size_t)(kt + 1) * 64 * HDIM;
            #pragma unroll
            for (int nt = 0; nt < 4; ++nt) {
                kf[nt * 2 + 0] = *(const uint4*)(kn + nt * 16 * HDIM);
                kf[nt * 2 + 1] = *(const uint4*)(kn + nt * 16 * HDIM + 32);
            }
        }

        asm volatile("s_waitcnt lgkmcnt(0)" ::: "memory");  // wave-local Ps ready

        const int kbmax = min(1, (qw0 + 15 - k0) >> 5);     // >= 0
        for (int kb = 0; kb <= kbmax; ++kb) {
            const bf16x8_t ap = frag_ld(&Ps[w][colL][kb * 32 + quad * 8]);
            #pragma unroll
            for (int dt = 0; dt < 4; ++dt)
                O[dt] = __builtin_amdgcn_mfma_f32_16x16x32_bf16(
                    ap, asfrag(vf[dt * 2 + kb]), O[dt], 0, 0, 0);
        }
    }

    // deferred l reduction over the 16 lanes of each quad-row
    float inv[4];
    #pragma unroll
    for (int r = 0; r < 4; ++r) {
        float s = lsum[r];
        #pragma unroll
        for (int off = 1; off < 16; off <<= 1) s += __shfl_xor(s, off);
        inv[r] = 1.0f / s;
    }

    // epilogue: O -> per-wave LDS -> coalesced uint4 stores
    #pragma unroll
    for (int dt = 0; dt < 4; ++dt)
        #pragma unroll
        for (int r = 0; r < 4; ++r)
            Ps[w][quad * 4 + r][dt * 16 + colL] = f2bf(O[dt][r] * inv[r]);
    asm volatile("s_waitcnt lgkmcnt(0)" ::: "memory");
    #pragma unroll
    for (int p = 0; p < 2; ++p) {
        const int rowl = (L >> 3) + 8 * p;      // 0..15
        const int c8 = (L & 7) * 8;             // 0..56
        const int s = qw0 + rowl;
        *(uint4*)&AO[((size_t)bb * SEQ + s) * D_MODEL + hh * HDIM + c8] =
            *(const uint4*)&Ps[w][rowl][c8];
    }
}

// ---------------------------------------------------------------------------
// Output projection: Out(fp32) = AO(bf16, 4096x1024) * Wo^T(fp32->bf16).
// ---------------------------------------------------------------------------
__global__ __launch_bounds__(256) void out_proj_kernel(
    const u16* __restrict__ A, const float* __restrict__ Wo, float* __restrict__ Out)
{
    __shared__ __align__(16) u16 As[128][72];
    __shared__ __align__(16) u16 Bs[128][72];
    const int tid = threadIdx.x;
    const int m0 = blockIdx.y * 128;
    const int n0 = blockIdx.x * 128;

    const int w = tid >> 6, L = tid & 63, quad = L >> 4, colL = L & 15;
    const int mw = (w & 1) * 64, nw = (w >> 1) * 64;
    const int srow = tid >> 3, skc = (tid & 7) * 8;

    f32x4_t acc[4][4];
    #pragma unroll
    for (int i = 0; i < 4; ++i)
        #pragma unroll
        for (int j = 0; j < 4; ++j) acc[i][j] = (f32x4_t){0.f, 0.f, 0.f, 0.f};

    for (int k0 = 0; k0 < D_MODEL; k0 += 64) {
        uint4 ar[4], br[4];
        #pragma unroll
        for (int p2 = 0; p2 < 4; ++p2) {
            const int row = srow + 32 * p2;
            ar[p2] = *(const uint4*)(A + (size_t)(m0 + row) * D_MODEL + k0 + skc);
            const float* wp = Wo + (size_t)(n0 + row) * D_MODEL + k0 + skc;
            br[p2] = pack8(*(const float4*)wp, *(const float4*)(wp + 4));
        }
        __syncthreads();
        #pragma unroll
        for (int p2 = 0; p2 < 4; ++p2) {
            const int row = srow + 32 * p2;
            *(uint4*)&As[row][skc] = ar[p2];
            *(uint4*)&Bs[row][skc] = br[p2];
        }
        __syncthreads();
        #pragma unroll
        for (int kb = 0; kb < 2; ++kb) {
            bf16x8_t af[4], bf[4];
            #pragma unroll
            for (int t = 0; t < 4; ++t) {
                af[t] = frag_ld(&As[mw + t * 16 + colL][kb * 32 + quad * 8]);
                bf[t] = frag_ld(&Bs[nw + t * 16 + colL][kb * 32 + quad * 8]);
            }
            #pragma unroll
            for (int mt = 0; mt < 4; ++mt)
                #pragma unroll
                for (int nt = 0; nt < 4; ++nt)
                    acc[mt][nt] = __builtin_amdgcn_mfma_f32_16x16x32_bf16(
                        af[mt], bf[nt], acc[mt][nt], 0, 0, 0);
        }
    }

    #pragma unroll
    for (int mt = 0; mt < 4; ++mt)
        #pragma unroll
        for (int nt = 0; nt < 4; ++nt)
            #pragma unroll
            for (int r = 0; r < 4; ++r) {
                const int m = m0 + mw + mt * 16 + quad * 4 + r;
                const int n = n0 + nw + nt * 16 + colL;
                Out[(size_t)m * D_MODEL + n] = acc[mt][nt][r];
            }
}

// ---------------------------------------------------------------------------
extern "C" void kernel_launch(void* const* d_in, const int* in_sizes, int n_in,
                              void* d_out, int out_size, void* d_ws, size_t ws_size,
                              hipStream_t stream) {
    const float* x  = (const float*)d_in[0];
    const float* wq = (const float*)d_in[1];
    const float* wk = (const float*)d_in[2];
    const float* wv = (const float*)d_in[3];
    const float* wo = (const float*)d_in[4];
    const int* pos  = (const int*)d_in[5];
    float* out = (float*)d_out;

    const size_t NELEM = (size_t)BATCH * NHEADS * SEQ * HDIM;  // 4,194,304
    u16* Qw  = (u16*)d_ws;
    u16* Kw  = Qw + NELEM;
    u16* Vtw = Kw + NELEM;
    u16* AOw = Vtw + NELEM;

    qkv_rope_kernel<<<dim3(24, 32), 256, 0, stream>>>(x, wq, wk, wv, pos, Qw, Kw, Vtw);
    attn_kernel<<<dim3(SEQ / 64, NHEADS, BATCH), 256, 0, stream>>>(Qw, Kw, Vtw, AOw);
    out_proj_kernel<<<dim3(8, 32), 256, 0, stream>>>(AOw, wo, out);
}

// Round 9
// 258.810 us; speedup vs baseline: 2.8773x; 2.8773x over previous
//
#include <hip/hip_runtime.h>
#include <hip/hip_bf16.h>

// MultiHeadSelfAttention: B=2, S=2048, D=1024, H=16, Dh=64, RoPE theta=1e4, causal.
// Round 9: attn reverted to round-6 (108us known-good; round-8 global-frag attn lost
// the 4x cross-wave K/V reuse -> 484MB FETCH). qkv/out_proj rebuilt m97-style:
// fp32 inputs pre-converted to bf16 (conv kernel), staging via global_load_lds
// width=16 into raw LDS with XOR chunk swizzle (conflict-free ds_read_b128).
// ws (u16): Q|K|Vt|AO(=Xbf alias)|Wbf = 20M elems = 40 MB.

#define D_MODEL 1024
#define NHEADS  16
#define HDIM    64
#define SEQ     2048
#define BATCH   2

typedef unsigned short u16;
typedef __bf16 bf16x8_t __attribute__((ext_vector_type(8)));
typedef float  f32x4_t  __attribute__((ext_vector_type(4)));

__device__ __forceinline__ u16 f2bf(float f) {
    union { __hip_bfloat16 h; u16 u; } cv;
    cv.h = __float2bfloat16(f);
    return cv.u;
}

__device__ __forceinline__ unsigned pk2(float x, float y) {
    union { __hip_bfloat162 h; unsigned u; } cv;
    cv.h = __float22bfloat162_rn(make_float2(x, y));   // v_cvt_pk_bf16_f32
    return cv.u;
}

__device__ __forceinline__ uint4 pack8(float4 a, float4 b) {
    uint4 u;
    u.x = pk2(a.x, a.y);
    u.y = pk2(a.z, a.w);
    u.z = pk2(b.x, b.y);
    u.w = pk2(b.z, b.w);
    return u;
}

__device__ __forceinline__ bf16x8_t frag_ld(const u16* p) {
    union { uint4 u; bf16x8_t v; } t;
    t.u = *(const uint4*)p;
    return t.v;
}

// async global->LDS DMA, 16B/lane; LDS dest = wave-uniform base + lane*16
__device__ __forceinline__ void dma16(const u16* g, u16* l) {
    __builtin_amdgcn_global_load_lds(
        (const __attribute__((address_space(1))) void*)g,
        (__attribute__((address_space(3))) void*)l, 16, 0, 0);
}

// ---------------------------------------------------------------------------
// fp32 -> bf16 conversion: X (4M elems) -> Xbf, Wq|Wk|Wv|Wo (1M each) -> Wbf.
// 1M threads x 8 elems. Pure bandwidth (~64 MB traffic).
// ---------------------------------------------------------------------------
__global__ __launch_bounds__(256) void conv_bf16_kernel(
    const float* __restrict__ X, const float* __restrict__ Wq,
    const float* __restrict__ Wk, const float* __restrict__ Wv,
    const float* __restrict__ Wo, u16* __restrict__ Xbf, u16* __restrict__ Wbf)
{
    const size_t gid = (size_t)blockIdx.x * 256 + threadIdx.x;
    const float* src;
    u16* dst;
    size_t off;
    if (gid < (1u << 19)) {                     // X: 4M elems / 8
        src = X; dst = Xbf; off = gid;
    } else {
        size_t g = gid - (1u << 19);
        const int wsel = (int)(g >> 17);        // 1M elems / 8 per W
        g &= (1u << 17) - 1;
        src = (wsel == 0) ? Wq : (wsel == 1) ? Wk : (wsel == 2) ? Wv : Wo;
        dst = Wbf + ((size_t)wsel << 20);
        off = g;
    }
    const float4 a = *(const float4*)(src + off * 8);
    const float4 b = *(const float4*)(src + off * 8 + 4);
    *(uint4*)(dst + off * 8) = pack8(a, b);
}

// ---------------------------------------------------------------------------
// QKV projection + RoPE, m97-style staging. C = Xbf(4096x1024)*W^T, virtual N=3072.
// 128x128 tile, BK=64, 4 waves 2x2. LDS raw [128][64] per operand, XOR-swizzled
// chunks: LDS[row][c] holds global chunk c^(row&7) -> DMA contiguous AND
// ds_read_b128 frags 2-way/bank (free). Q pre-scaled 1/8; V stored transposed.
// ---------------------------------------------------------------------------
__global__ __launch_bounds__(256) void qkv_rope_kernel(
    const u16* __restrict__ Xbf, const u16* __restrict__ Wbf,
    const int* __restrict__ pos,
    u16* __restrict__ Qo, u16* __restrict__ Ko, u16* __restrict__ Vt)
{
    __shared__ __align__(16) u16 smem[16896];   // staging 2x8192 ∪ Ts 128x132
    u16* As = smem;                             // [128][64] raw
    u16* Bs = smem + 8192;

    const int tid = threadIdx.x;
    const int m0 = blockIdx.y * 128;
    const int nv = blockIdx.x * 128;
    const int which = nv >> 10;                 // 0=q,1=k,2=v
    const int nbase = nv & 1023;
    const u16* __restrict__ Wsrc = Wbf + ((size_t)which << 20);

    const int w = tid >> 6, L = tid & 63, quad = L >> 4, colL = L & 15;
    const int mw = (w & 1) * 64, nw = (w >> 1) * 64;

    // DMA addressing: wave w, instr j stages rows 32w+8j .. +7 (8 rows x 128B).
    // lane L: row_l = L>>3, source chunk = (L&7) ^ row_l  (XOR swizzle).
    const int lrow = L >> 3;
    const int lchk = (L & 7) ^ lrow;
    const u16* ag = Xbf + (size_t)(m0 + 32 * w + lrow) * D_MODEL + lchk * 8;
    const u16* bg = Wsrc + (size_t)(nbase + 32 * w + lrow) * D_MODEL + lchk * 8;
    u16* al = As + (32 * w) * 64;               // wave-uniform LDS bases
    u16* bl = Bs + (32 * w) * 64;

    f32x4_t acc[4][4];
    #pragma unroll
    for (int i = 0; i < 4; ++i)
        #pragma unroll
        for (int j = 0; j < 4; ++j) acc[i][j] = (f32x4_t){0.f, 0.f, 0.f, 0.f};

    for (int k0 = 0; k0 < D_MODEL; k0 += 64) {
        __syncthreads();                        // prev iter frag reads done
        #pragma unroll
        for (int j = 0; j < 4; ++j) {
            dma16(ag + (size_t)j * 8 * D_MODEL + k0, al + j * 512);
            dma16(bg + (size_t)j * 8 * D_MODEL + k0, bl + j * 512);
        }
        __syncthreads();                        // drains vmcnt (DMA complete)
        #pragma unroll
        for (int kb = 0; kb < 2; ++kb) {
            const int ch = ((kb * 4 + quad) ^ (colL & 7)) * 8;
            bf16x8_t af[4], bf[4];
            #pragma unroll
            for (int t = 0; t < 4; ++t) {
                af[t] = frag_ld(As + (mw + t * 16 + colL) * 64 + ch);
                bf[t] = frag_ld(Bs + (nw + t * 16 + colL) * 64 + ch);
            }
            #pragma unroll
            for (int mt = 0; mt < 4; ++mt)
                #pragma unroll
                for (int nt = 0; nt < 4; ++nt)
                    acc[mt][nt] = __builtin_amdgcn_mfma_f32_16x16x32_bf16(
                        af[mt], bf[nt], acc[mt][nt], 0, 0, 0);
        }
    }

    // ---- epilogue: RoPE (regs) -> LDS tile -> coalesced stores ----
    __syncthreads();                            // done with As/Bs
    u16 (*Ts)[132] = (u16(*)[132])smem;         // 128x132 u16 = 33792 B

    const float C0 = 0.14391156831212787f;      // ln(10000)/64
    if (which < 2) {
        const float oscale = (which == 0) ? 0.125f : 1.0f;   // fold 1/sqrt(64) into Q
        float invf[4], sgn[4];
        #pragma unroll
        for (int nt = 0; nt < 4; ++nt) {
            const int n = nbase + nw + nt * 16 + colL;
            const int dd = n & 63;
            invf[nt] = __expf(-(float)(dd & 62) * C0);
            sgn[nt] = (dd & 1) ? 1.0f : -1.0f;
        }
        #pragma unroll
        for (int mt = 0; mt < 4; ++mt) {
            #pragma unroll
            for (int r = 0; r < 4; ++r) {
                const int ml = mw + mt * 16 + quad * 4 + r;
                const int ss = (m0 + ml) & 2047;
                const float p = (float)pos[ss];
                #pragma unroll
                for (int nt = 0; nt < 4; ++nt) {
                    const float v = acc[mt][nt][r];
                    const float partner = __shfl_xor(v, 1);
                    float sn, cs;
                    __sincosf(p * invf[nt], &sn, &cs);
                    Ts[ml][nw + nt * 16 + colL] =
                        f2bf((v * cs + sgn[nt] * sn * partner) * oscale);
                }
            }
        }
    } else {
        #pragma unroll
        for (int mt = 0; mt < 4; ++mt)
            #pragma unroll
            for (int nt = 0; nt < 4; ++nt)
                #pragma unroll
                for (int r = 0; r < 4; ++r)
                    Ts[nw + nt * 16 + colL][mw + mt * 16 + quad * 4 + r] = f2bf(acc[mt][nt][r]);
    }
    __syncthreads();

    const int rr0 = tid >> 4;                   // 0..15
    const int cc8 = (tid & 15) * 8;             // 0..120
    if (which < 2) {
        u16* __restrict__ dst = (which == 0) ? Qo : Ko;
        #pragma unroll
        for (int it = 0; it < 8; ++it) {
            const int ml = rr0 + it * 16;
            const int m = m0 + ml, bb = m >> 11, ss = m & 2047;
            const int n = nbase + cc8, h = n >> 6, d = n & 63;
            *(uint4*)&dst[((size_t)(bb * NHEADS + h) * SEQ + ss) * HDIM + d] =
                *(const uint4*)&Ts[ml][cc8];
        }
    } else {
        const int bb = m0 >> 11, ss0 = (m0 & 2047) + cc8;
        #pragma unroll
        for (int it = 0; it < 8; ++it) {
            const int nl = rr0 + it * 16;
            const int n = nbase + nl, h = n >> 6, d = n & 63;
            *(uint4*)&Vt[((size_t)(bb * NHEADS + h) * HDIM + d) * SEQ + ss0] =
                *(const uint4*)&Ts[nl][cc8];
        }
    }
}

// ---------------------------------------------------------------------------
// Flash attention, causal, MFMA, max-free softmax (round-6 version, 108us).
// Block = (b, h, 64-q-tile), 4 waves x 16 q-rows. K/V reg-prefetched.
// ---------------------------------------------------------------------------
__global__ __launch_bounds__(256) void attn_kernel(
    const u16* __restrict__ Q, const u16* __restrict__ K,
    const u16* __restrict__ Vt, u16* __restrict__ AO)
{
    __shared__ __align__(16) u16 Qs[64][72];    // [q][d]
    __shared__ __align__(16) u16 Ks[64][72];    // [key][d]
    __shared__ __align__(16) u16 Vs[64][72];    // [d][key]
    __shared__ __align__(16) u16 Ps[4][16][72]; // per-wave [q_local][key]

    const int tid = threadIdx.x;
    const int qt = (int)gridDim.x - 1 - (int)blockIdx.x;  // long blocks first
    const int hh = blockIdx.y, bb = blockIdx.z;
    const size_t bh = ((size_t)bb * NHEADS + hh) * (SEQ * HDIM);
    const int q0 = qt * 64;

    const int w = tid >> 6, L = tid & 63, quad = L >> 4, colL = L & 15;
    const int srow = tid >> 2, sc = (tid & 3) * 16;

    {   // stage Q once (pre-scaled by 1/8 in qkv)
        const u16* qp = Q + bh + (size_t)(q0 + srow) * HDIM + sc;
        *(uint4*)&Qs[srow][sc]     = *(const uint4*)qp;
        *(uint4*)&Qs[srow][sc + 8] = *(const uint4*)(qp + 8);
    }

    float lsum[4] = {0.f, 0.f, 0.f, 0.f};
    f32x4_t O[4];
    #pragma unroll
    for (int dt = 0; dt < 4; ++dt) O[dt] = (f32x4_t){0.f, 0.f, 0.f, 0.f};

    // prefetch tile 0 into registers
    const u16* kp = K + bh + (size_t)srow * HDIM + sc;
    const u16* vp = Vt + bh + (size_t)srow * SEQ + sc;
    uint4 kv0 = *(const uint4*)kp;
    uint4 kv1 = *(const uint4*)(kp + 8);
    uint4 vv0 = *(const uint4*)vp;
    uint4 vv1 = *(const uint4*)(vp + 8);

    for (int kt = 0; kt <= qt; ++kt) {
        __syncthreads();                        // prev tile's frag reads done
        *(uint4*)&Ks[srow][sc]     = kv0;
        *(uint4*)&Ks[srow][sc + 8] = kv1;
        *(uint4*)&Vs[srow][sc]     = vv0;
        *(uint4*)&Vs[srow][sc + 8] = vv1;
        if (kt < qt) {                          // prefetch next tile
            const int k1 = (kt + 1) * 64;
            const u16* kpn = K + bh + (size_t)(k1 + srow) * HDIM + sc;
            kv0 = *(const uint4*)kpn;
            kv1 = *(const uint4*)(kpn + 8);
            const u16* vpn = Vt + bh + (size_t)srow * SEQ + k1 + sc;
            vv0 = *(const uint4*)vpn;
            vv1 = *(const uint4*)(vpn + 8);
        }
        __syncthreads();

        const bool diag = (kt == qt);
        const int ntmax = diag ? w : 3;         // wave-uniform causal pruning

        f32x4_t S[4];
        #pragma unroll
        for (int nt = 0; nt < 4; ++nt) S[nt] = (f32x4_t){0.f, 0.f, 0.f, 0.f};
        #pragma unroll
        for (int kb = 0; kb < 2; ++kb) {
            const bf16x8_t aq = frag_ld(&Qs[w * 16 + colL][kb * 32 + quad * 8]);
            for (int nt = 0; nt <= ntmax; ++nt) {
                const bf16x8_t bk = frag_ld(&Ks[nt * 16 + colL][kb * 32 + quad * 8]);
                S[nt] = __builtin_amdgcn_mfma_f32_16x16x32_bf16(aq, bk, S[nt], 0, 0, 0);
            }
        }

        // max-free: p = exp(s); per-lane partial l; masked/pruned -> 0
        #pragma unroll
        for (int r = 0; r < 4; ++r) {
            const int qa = q0 + w * 16 + quad * 4 + r;
            #pragma unroll
            for (int nt = 0; nt < 4; ++nt) {
                float pv = 0.0f;
                if (nt <= ntmax) {
                    const int key = kt * 64 + nt * 16 + colL;
                    pv = (!diag || key <= qa) ? __expf(S[nt][r]) : 0.0f;
                }
                lsum[r] += pv;
                Ps[w][quad * 4 + r][nt * 16 + colL] = f2bf(pv);
            }
        }

        asm volatile("s_waitcnt lgkmcnt(0)" ::: "memory");  // wave-local Ps ready

        const int kbmax = diag ? (w >> 1) : 1;
        #pragma unroll
        for (int kb = 0; kb < 2; ++kb) {
            if (kb > kbmax) break;
            const bf16x8_t ap = frag_ld(&Ps[w][colL][kb * 32 + quad * 8]);
            #pragma unroll
            for (int dt = 0; dt < 4; ++dt) {
                const bf16x8_t bv = frag_ld(&Vs[dt * 16 + colL][kb * 32 + quad * 8]);
                O[dt] = __builtin_amdgcn_mfma_f32_16x16x32_bf16(ap, bv, O[dt], 0, 0, 0);
            }
        }
    }

    // deferred l reduction over the 16 lanes of each quad-row
    float inv[4];
    #pragma unroll
    for (int r = 0; r < 4; ++r) {
        float s = lsum[r];
        #pragma unroll
        for (int off = 1; off < 16; off <<= 1) s += __shfl_xor(s, off);
        inv[r] = 1.0f / s;
    }

    // epilogue: O -> per-wave LDS -> coalesced uint4 stores
    #pragma unroll
    for (int dt = 0; dt < 4; ++dt)
        #pragma unroll
        for (int r = 0; r < 4; ++r)
            Ps[w][quad * 4 + r][dt * 16 + colL] = f2bf(O[dt][r] * inv[r]);
    asm volatile("s_waitcnt lgkmcnt(0)" ::: "memory");
    #pragma unroll
    for (int p = 0; p < 2; ++p) {
        const int rowl = (L >> 3) + 8 * p;      // 0..15
        const int c8 = (L & 7) * 8;             // 0..56
        const int s = q0 + w * 16 + rowl;
        *(uint4*)&AO[((size_t)bb * SEQ + s) * D_MODEL + hh * HDIM + c8] =
            *(const uint4*)&Ps[w][rowl][c8];
    }
}

// ---------------------------------------------------------------------------
// Output projection: Out(fp32) = AO(bf16) * Wo_bf^T, m97-style DMA staging.
// ---------------------------------------------------------------------------
__global__ __launch_bounds__(256) void out_proj_kernel(
    const u16* __restrict__ A, const u16* __restrict__ Wob, float* __restrict__ Out)
{
    __shared__ __align__(16) u16 smem[16384];   // 2x [128][64] raw
    u16* As = smem;
    u16* Bs = smem + 8192;

    const int tid = threadIdx.x;
    const int m0 = blockIdx.y * 128;
    const int n0 = blockIdx.x * 128;

    const int w = tid >> 6, L = tid & 63, quad = L >> 4, colL = L & 15;
    const int mw = (w & 1) * 64, nw = (w >> 1) * 64;

    const int lrow = L >> 3;
    const int lchk = (L & 7) ^ lrow;
    const u16* ag = A + (size_t)(m0 + 32 * w + lrow) * D_MODEL + lchk * 8;
    const u16* bg = Wob + (size_t)(n0 + 32 * w + lrow) * D_MODEL + lchk * 8;
    u16* al = As + (32 * w) * 64;
    u16* bl = Bs + (32 * w) * 64;

    f32x4_t acc[4][4];
    #pragma unroll
    for (int i = 0; i < 4; ++i)
        #pragma unroll
        for (int j = 0; j < 4; ++j) acc[i][j] = (f32x4_t){0.f, 0.f, 0.f, 0.f};

    for (int k0 = 0; k0 < D_MODEL; k0 += 64) {
        __syncthreads();
        #pragma unroll
        for (int j = 0; j < 4; ++j) {
            dma16(ag + (size_t)j * 8 * D_MODEL + k0, al + j * 512);
            dma16(bg + (size_t)j * 8 * D_MODEL + k0, bl + j * 512);
        }
        __syncthreads();
        #pragma unroll
        for (int kb = 0; kb < 2; ++kb) {
            const int ch = ((kb * 4 + quad) ^ (colL & 7)) * 8;
            bf16x8_t af[4], bf[4];
            #pragma unroll
            for (int t = 0; t < 4; ++t) {
                af[t] = frag_ld(As + (mw + t * 16 + colL) * 64 + ch);
                bf[t] = frag_ld(Bs + (nw + t * 16 + colL) * 64 + ch);
            }
            #pragma unroll
            for (int mt = 0; mt < 4; ++mt)
                #pragma unroll
                for (int nt = 0; nt < 4; ++nt)
                    acc[mt][nt] = __builtin_amdgcn_mfma_f32_16x16x32_bf16(
                        af[mt], bf[nt], acc[mt][nt], 0, 0, 0);
        }
    }

    #pragma unroll
    for (int mt = 0; mt < 4; ++mt)
        #pragma unroll
        for (int nt = 0; nt < 4; ++nt)
            #pragma unroll
            for (int r = 0; r < 4; ++r) {
                const int m = m0 + mw + mt * 16 + quad * 4 + r;
                const int n = n0 + nw + nt * 16 + colL;
                Out[(size_t)m * D_MODEL + n] = acc[mt][nt][r];
            }
}

// ---------------------------------------------------------------------------
extern "C" void kernel_launch(void* const* d_in, const int* in_sizes, int n_in,
                              void* d_out, int out_size, void* d_ws, size_t ws_size,
                              hipStream_t stream) {
    const float* x  = (const float*)d_in[0];
    const float* wq = (const float*)d_in[1];
    const float* wk = (const float*)d_in[2];
    const float* wv = (const float*)d_in[3];
    const float* wo = (const float*)d_in[4];
    const int* pos  = (const int*)d_in[5];
    float* out = (float*)d_out;

    const size_t NELEM = (size_t)BATCH * NHEADS * SEQ * HDIM;  // 4,194,304
    u16* Qw  = (u16*)d_ws;
    u16* Kw  = Qw + NELEM;
    u16* Vtw = Kw + NELEM;
    u16* AOw = Vtw + NELEM;        // doubles as Xbf (attn overwrites after qkv)
    u16* Xbf = AOw;
    u16* Wbf = AOw + NELEM;        // 4M elems (wq|wk|wv|wo) -> total ws 40 MB

    conv_bf16_kernel<<<4096, 256, 0, stream>>>(x, wq, wk, wv, wo, Xbf, Wbf);
    qkv_rope_kernel<<<dim3(24, 32), 256, 0, stream>>>(Xbf, Wbf, pos, Qw, Kw, Vtw);
    attn_kernel<<<dim3(SEQ / 64, NHEADS, BATCH), 256, 0, stream>>>(Qw, Kw, Vtw, AOw);
    out_proj_kernel<<<dim3(8, 32), 256, 0, stream>>>(AOw, Wbf + 3 * (1u << 20), out);
}

// Round 10
// 226.867 us; speedup vs baseline: 3.2824x; 1.1408x over previous
//
#include <hip/hip_runtime.h>
#include <hip/hip_bf16.h>

// MultiHeadSelfAttention: B=2, S=2048, D=1024, H=16, Dh=64, RoPE theta=1e4, causal.
// Round 10: flash-decoding split-K attention. Max-free softmax makes partials
// associative: chunks of <=8 k-tiles write unnormalized O(bf16)+l(fp32) partials;
// combine kernel sums+normalizes. Kills the triangular tail (serial len 32 -> 8).
// conv/qkv(DMA m97-style)/out_proj unchanged from round 9.
// ws (u16): Q|K|Vt|AO(=Xbf)|Wbf (40MB) + Opart 2560x4096 u16 (21MB) + Lpart (0.7MB).

#define D_MODEL 1024
#define NHEADS  16
#define HDIM    64
#define SEQ     2048
#define BATCH   2

typedef unsigned short u16;
typedef __bf16 bf16x8_t __attribute__((ext_vector_type(8)));
typedef float  f32x4_t  __attribute__((ext_vector_type(4)));

__device__ __forceinline__ u16 f2bf(float f) {
    union { __hip_bfloat16 h; u16 u; } cv;
    cv.h = __float2bfloat16(f);
    return cv.u;
}

__device__ __forceinline__ unsigned pk2(float x, float y) {
    union { __hip_bfloat162 h; unsigned u; } cv;
    cv.h = __float22bfloat162_rn(make_float2(x, y));   // v_cvt_pk_bf16_f32
    return cv.u;
}

__device__ __forceinline__ uint4 pack8(float4 a, float4 b) {
    uint4 u;
    u.x = pk2(a.x, a.y);
    u.y = pk2(a.z, a.w);
    u.z = pk2(b.x, b.y);
    u.w = pk2(b.z, b.w);
    return u;
}

__device__ __forceinline__ bf16x8_t frag_ld(const u16* p) {
    union { uint4 u; bf16x8_t v; } t;
    t.u = *(const uint4*)p;
    return t.v;
}

// unpack 4 bf16-pairs (uint4) -> add into 8 fp32 accumulators
__device__ __forceinline__ void acc8(uint4 u, float* a) {
    a[0] += __uint_as_float(u.x << 16); a[1] += __uint_as_float(u.x & 0xffff0000u);
    a[2] += __uint_as_float(u.y << 16); a[3] += __uint_as_float(u.y & 0xffff0000u);
    a[4] += __uint_as_float(u.z << 16); a[5] += __uint_as_float(u.z & 0xffff0000u);
    a[6] += __uint_as_float(u.w << 16); a[7] += __uint_as_float(u.w & 0xffff0000u);
}

// async global->LDS DMA, 16B/lane; LDS dest = wave-uniform base + lane*16
__device__ __forceinline__ void dma16(const u16* g, u16* l) {
    __builtin_amdgcn_global_load_lds(
        (const __attribute__((address_space(1))) void*)g,
        (__attribute__((address_space(3))) void*)l, 16, 0, 0);
}

// ---------------------------------------------------------------------------
// fp32 -> bf16 conversion: X (4M elems) -> Xbf, Wq|Wk|Wv|Wo (1M each) -> Wbf.
// ---------------------------------------------------------------------------
__global__ __launch_bounds__(256) void conv_bf16_kernel(
    const float* __restrict__ X, const float* __restrict__ Wq,
    const float* __restrict__ Wk, const float* __restrict__ Wv,
    const float* __restrict__ Wo, u16* __restrict__ Xbf, u16* __restrict__ Wbf)
{
    const size_t gid = (size_t)blockIdx.x * 256 + threadIdx.x;
    const float* src;
    u16* dst;
    size_t off;
    if (gid < (1u << 19)) {                     // X: 4M elems / 8
        src = X; dst = Xbf; off = gid;
    } else {
        size_t g = gid - (1u << 19);
        const int wsel = (int)(g >> 17);        // 1M elems / 8 per W
        g &= (1u << 17) - 1;
        src = (wsel == 0) ? Wq : (wsel == 1) ? Wk : (wsel == 2) ? Wv : Wo;
        dst = Wbf + ((size_t)wsel << 20);
        off = g;
    }
    const float4 a = *(const float4*)(src + off * 8);
    const float4 b = *(const float4*)(src + off * 8 + 4);
    *(uint4*)(dst + off * 8) = pack8(a, b);
}

// ---------------------------------------------------------------------------
// QKV projection + RoPE, m97-style DMA staging (round 9, unchanged).
// ---------------------------------------------------------------------------
__global__ __launch_bounds__(256) void qkv_rope_kernel(
    const u16* __restrict__ Xbf, const u16* __restrict__ Wbf,
    const int* __restrict__ pos,
    u16* __restrict__ Qo, u16* __restrict__ Ko, u16* __restrict__ Vt)
{
    __shared__ __align__(16) u16 smem[16896];   // staging 2x8192 ∪ Ts 128x132
    u16* As = smem;                             // [128][64] raw
    u16* Bs = smem + 8192;

    const int tid = threadIdx.x;
    const int m0 = blockIdx.y * 128;
    const int nv = blockIdx.x * 128;
    const int which = nv >> 10;                 // 0=q,1=k,2=v
    const int nbase = nv & 1023;
    const u16* __restrict__ Wsrc = Wbf + ((size_t)which << 20);

    const int w = tid >> 6, L = tid & 63, quad = L >> 4, colL = L & 15;
    const int mw = (w & 1) * 64, nw = (w >> 1) * 64;

    const int lrow = L >> 3;
    const int lchk = (L & 7) ^ lrow;            // XOR chunk swizzle
    const u16* ag = Xbf + (size_t)(m0 + 32 * w + lrow) * D_MODEL + lchk * 8;
    const u16* bg = Wsrc + (size_t)(nbase + 32 * w + lrow) * D_MODEL + lchk * 8;
    u16* al = As + (32 * w) * 64;
    u16* bl = Bs + (32 * w) * 64;

    f32x4_t acc[4][4];
    #pragma unroll
    for (int i = 0; i < 4; ++i)
        #pragma unroll
        for (int j = 0; j < 4; ++j) acc[i][j] = (f32x4_t){0.f, 0.f, 0.f, 0.f};

    for (int k0 = 0; k0 < D_MODEL; k0 += 64) {
        __syncthreads();
        #pragma unroll
        for (int j = 0; j < 4; ++j) {
            dma16(ag + (size_t)j * 8 * D_MODEL + k0, al + j * 512);
            dma16(bg + (size_t)j * 8 * D_MODEL + k0, bl + j * 512);
        }
        __syncthreads();
        #pragma unroll
        for (int kb = 0; kb < 2; ++kb) {
            const int ch = ((kb * 4 + quad) ^ (colL & 7)) * 8;
            bf16x8_t af[4], bf[4];
            #pragma unroll
            for (int t = 0; t < 4; ++t) {
                af[t] = frag_ld(As + (mw + t * 16 + colL) * 64 + ch);
                bf[t] = frag_ld(Bs + (nw + t * 16 + colL) * 64 + ch);
            }
            #pragma unroll
            for (int mt = 0; mt < 4; ++mt)
                #pragma unroll
                for (int nt = 0; nt < 4; ++nt)
                    acc[mt][nt] = __builtin_amdgcn_mfma_f32_16x16x32_bf16(
                        af[mt], bf[nt], acc[mt][nt], 0, 0, 0);
        }
    }

    __syncthreads();
    u16 (*Ts)[132] = (u16(*)[132])smem;

    const float C0 = 0.14391156831212787f;      // ln(10000)/64
    if (which < 2) {
        const float oscale = (which == 0) ? 0.125f : 1.0f;
        float invf[4], sgn[4];
        #pragma unroll
        for (int nt = 0; nt < 4; ++nt) {
            const int n = nbase + nw + nt * 16 + colL;
            const int dd = n & 63;
            invf[nt] = __expf(-(float)(dd & 62) * C0);
            sgn[nt] = (dd & 1) ? 1.0f : -1.0f;
        }
        #pragma unroll
        for (int mt = 0; mt < 4; ++mt) {
            #pragma unroll
            for (int r = 0; r < 4; ++r) {
                const int ml = mw + mt * 16 + quad * 4 + r;
                const int ss = (m0 + ml) & 2047;
                const float p = (float)pos[ss];
                #pragma unroll
                for (int nt = 0; nt < 4; ++nt) {
                    const float v = acc[mt][nt][r];
                    const float partner = __shfl_xor(v, 1);
                    float sn, cs;
                    __sincosf(p * invf[nt], &sn, &cs);
                    Ts[ml][nw + nt * 16 + colL] =
                        f2bf((v * cs + sgn[nt] * sn * partner) * oscale);
                }
            }
        }
    } else {
        #pragma unroll
        for (int mt = 0; mt < 4; ++mt)
            #pragma unroll
            for (int nt = 0; nt < 4; ++nt)
                #pragma unroll
                for (int r = 0; r < 4; ++r)
                    Ts[nw + nt * 16 + colL][mw + mt * 16 + quad * 4 + r] = f2bf(acc[mt][nt][r]);
    }
    __syncthreads();

    const int rr0 = tid >> 4;
    const int cc8 = (tid & 15) * 8;
    if (which < 2) {
        u16* __restrict__ dst = (which == 0) ? Qo : Ko;
        #pragma unroll
        for (int it = 0; it < 8; ++it) {
            const int ml = rr0 + it * 16;
            const int m = m0 + ml, bb = m >> 11, ss = m & 2047;
            const int n = nbase + cc8, h = n >> 6, d = n & 63;
            *(uint4*)&dst[((size_t)(bb * NHEADS + h) * SEQ + ss) * HDIM + d] =
                *(const uint4*)&Ts[ml][cc8];
        }
    } else {
        const int bb = m0 >> 11, ss0 = (m0 & 2047) + cc8;
        #pragma unroll
        for (int it = 0; it < 8; ++it) {
            const int nl = rr0 + it * 16;
            const int n = nbase + nl, h = n >> 6, d = n & 63;
            *(uint4*)&Vt[((size_t)(bb * NHEADS + h) * HDIM + d) * SEQ + ss0] =
                *(const uint4*)&Ts[nl][cc8];
        }
    }
}

// ---------------------------------------------------------------------------
// Split-K flash attention (causal, max-free). Block = (slot, h, b) where slot
// encodes (qt, s): chunk s covers k-tiles [8s, min(8s+8, qt+1)). Writes
// unnormalized O partial (bf16) + l partial (fp32). 4 waves x 16 q-rows.
// slot layout per (b,h): qt=8g+r has g+1 chunks; base(qt)=4g(g+1)+r(g+1); 80 total.
// ---------------------------------------------------------------------------
__global__ __launch_bounds__(256) void attn_kernel(
    const u16* __restrict__ Q, const u16* __restrict__ K,
    const u16* __restrict__ Vt, u16* __restrict__ Opart, float* __restrict__ Lpart)
{
    __shared__ __align__(16) u16 Qs[64][72];    // [q][d]
    __shared__ __align__(16) u16 Ks[64][72];    // [key][d]
    __shared__ __align__(16) u16 Vs[64][72];    // [d][key]
    __shared__ __align__(16) u16 Ps[4][16][72]; // per-wave [q_local][key]

    const int tid = threadIdx.x;
    const int slot = 79 - (int)blockIdx.x;      // LPT: deepest chunks first
    const int g = (slot >= 48) ? 3 : (slot >= 24) ? 2 : (slot >= 8) ? 1 : 0;
    const int t0 = slot - 4 * g * (g + 1);
    const int rr = t0 / (g + 1);
    const int s  = t0 - rr * (g + 1);
    const int qt = 8 * g + rr;

    const int hh = blockIdx.y, bb = blockIdx.z;
    const size_t bh = ((size_t)bb * NHEADS + hh) * (SEQ * HDIM);
    const int q0 = qt * 64;
    const int kt0 = s * 8;
    const int ktend = min(kt0 + 8, qt + 1);
    const size_t gslot = ((size_t)(bb * NHEADS + hh) * 80 + slot);

    const int w = tid >> 6, L = tid & 63, quad = L >> 4, colL = L & 15;
    const int srow = tid >> 2, sc = (tid & 3) * 16;

    {   // stage Q once (pre-scaled by 1/8 in qkv)
        const u16* qp = Q + bh + (size_t)(q0 + srow) * HDIM + sc;
        *(uint4*)&Qs[srow][sc]     = *(const uint4*)qp;
        *(uint4*)&Qs[srow][sc + 8] = *(const uint4*)(qp + 8);
    }

    float lsum[4] = {0.f, 0.f, 0.f, 0.f};
    f32x4_t O[4];
    #pragma unroll
    for (int dt = 0; dt < 4; ++dt) O[dt] = (f32x4_t){0.f, 0.f, 0.f, 0.f};

    // prefetch first tile of this chunk
    const u16* kp = K + bh + (size_t)(kt0 * 64 + srow) * HDIM + sc;
    const u16* vp = Vt + bh + (size_t)srow * SEQ + kt0 * 64 + sc;
    uint4 kv0 = *(const uint4*)kp;
    uint4 kv1 = *(const uint4*)(kp + 8);
    uint4 vv0 = *(const uint4*)vp;
    uint4 vv1 = *(const uint4*)(vp + 8);

    for (int kt = kt0; kt < ktend; ++kt) {
        __syncthreads();                        // prev tile's frag reads done
        *(uint4*)&Ks[srow][sc]     = kv0;
        *(uint4*)&Ks[srow][sc + 8] = kv1;
        *(uint4*)&Vs[srow][sc]     = vv0;
        *(uint4*)&Vs[srow][sc + 8] = vv1;
        if (kt + 1 < ktend) {                   // prefetch next tile
            const int k1 = (kt + 1) * 64;
            const u16* kpn = K + bh + (size_t)(k1 + srow) * HDIM + sc;
            kv0 = *(const uint4*)kpn;
            kv1 = *(const uint4*)(kpn + 8);
            const u16* vpn = Vt + bh + (size_t)srow * SEQ + k1 + sc;
            vv0 = *(const uint4*)vpn;
            vv1 = *(const uint4*)(vpn + 8);
        }
        __syncthreads();

        const bool diag = (kt == qt);
        const int ntmax = diag ? w : 3;         // wave-uniform causal pruning

        f32x4_t S[4];
        #pragma unroll
        for (int nt = 0; nt < 4; ++nt) S[nt] = (f32x4_t){0.f, 0.f, 0.f, 0.f};
        #pragma unroll
        for (int kb = 0; kb < 2; ++kb) {
            const bf16x8_t aq = frag_ld(&Qs[w * 16 + colL][kb * 32 + quad * 8]);
            for (int nt = 0; nt <= ntmax; ++nt) {
                const bf16x8_t bk = frag_ld(&Ks[nt * 16 + colL][kb * 32 + quad * 8]);
                S[nt] = __builtin_amdgcn_mfma_f32_16x16x32_bf16(aq, bk, S[nt], 0, 0, 0);
            }
        }

        // max-free: p = exp(s); per-lane partial l; masked/pruned -> 0
        #pragma unroll
        for (int r = 0; r < 4; ++r) {
            const int qa = q0 + w * 16 + quad * 4 + r;
            #pragma unroll
            for (int nt = 0; nt < 4; ++nt) {
                float pv = 0.0f;
                if (nt <= ntmax) {
                    const int key = kt * 64 + nt * 16 + colL;
                    pv = (!diag || key <= qa) ? __expf(S[nt][r]) : 0.0f;
                }
                lsum[r] += pv;
                Ps[w][quad * 4 + r][nt * 16 + colL] = f2bf(pv);
            }
        }

        asm volatile("s_waitcnt lgkmcnt(0)" ::: "memory");  // wave-local Ps ready

        const int kbmax = diag ? (w >> 1) : 1;
        #pragma unroll
        for (int kb = 0; kb < 2; ++kb) {
            if (kb > kbmax) break;
            const bf16x8_t ap = frag_ld(&Ps[w][colL][kb * 32 + quad * 8]);
            #pragma unroll
            for (int dt = 0; dt < 4; ++dt) {
                const bf16x8_t bv = frag_ld(&Vs[dt * 16 + colL][kb * 32 + quad * 8]);
                O[dt] = __builtin_amdgcn_mfma_f32_16x16x32_bf16(ap, bv, O[dt], 0, 0, 0);
            }
        }
    }

    // l partial: reduce over the 16 lanes of each quad-row; lane colL==0 writes
    #pragma unroll
    for (int r = 0; r < 4; ++r) {
        float sm = lsum[r];
        #pragma unroll
        for (int off = 1; off < 16; off <<= 1) sm += __shfl_xor(sm, off);
        if (colL == 0)
            Lpart[gslot * 64 + 16 * w + quad * 4 + r] = sm;
    }

    // O partial (unnormalized bf16): C-layout -> per-wave LDS -> coalesced stores
    #pragma unroll
    for (int dt = 0; dt < 4; ++dt)
        #pragma unroll
        for (int r = 0; r < 4; ++r)
            Ps[w][quad * 4 + r][dt * 16 + colL] = f2bf(O[dt][r]);
    asm volatile("s_waitcnt lgkmcnt(0)" ::: "memory");
    #pragma unroll
    for (int p = 0; p < 2; ++p) {
        const int rowl = (L >> 3) + 8 * p;      // 0..15
        const int c8 = (L & 7) * 8;             // 0..56
        *(uint4*)&Opart[gslot * 4096 + (size_t)(16 * w + rowl) * 64 + c8] =
            *(const uint4*)&Ps[w][rowl][c8];
    }
}

// ---------------------------------------------------------------------------
// Combine: AO[b,s,h*d] = (sum_s Opart) / (sum_s Lpart). Block = (qt, hh, bb).
// Thread t: q = t>>2, 16 d's at (t&3)*16.
// ---------------------------------------------------------------------------
__global__ __launch_bounds__(256) void combine_kernel(
    const u16* __restrict__ Opart, const float* __restrict__ Lpart,
    u16* __restrict__ AO)
{
    const int qt = blockIdx.x, hh = blockIdx.y, bb = blockIdx.z;
    const int g = qt >> 3;
    const int nsplit = g + 1;
    const int base = 4 * g * (g + 1) + (qt & 7) * (g + 1);
    const int t = threadIdx.x;
    const int q = t >> 2, dg = (t & 3) * 16;
    const size_t slot0 = (size_t)(bb * NHEADS + hh) * 80 + base;

    float acc[16];
    #pragma unroll
    for (int i = 0; i < 16; ++i) acc[i] = 0.f;
    float l = 0.f;
    for (int s = 0; s < nsplit; ++s) {
        const size_t gs = slot0 + s;
        l += Lpart[gs * 64 + q];
        const u16* op = Opart + gs * 4096 + (size_t)q * 64 + dg;
        acc8(*(const uint4*)op, acc);
        acc8(*(const uint4*)(op + 8), acc + 8);
    }
    const float inv = 1.0f / l;
    uint4 o0, o1;
    o0.x = pk2(acc[0] * inv, acc[1] * inv);  o0.y = pk2(acc[2] * inv, acc[3] * inv);
    o0.z = pk2(acc[4] * inv, acc[5] * inv);  o0.w = pk2(acc[6] * inv, acc[7] * inv);
    o1.x = pk2(acc[8] * inv, acc[9] * inv);  o1.y = pk2(acc[10] * inv, acc[11] * inv);
    o1.z = pk2(acc[12] * inv, acc[13] * inv); o1.w = pk2(acc[14] * inv, acc[15] * inv);
    u16* dst = AO + ((size_t)bb * SEQ + qt * 64 + q) * D_MODEL + hh * HDIM + dg;
    *(uint4*)dst = o0;
    *(uint4*)(dst + 8) = o1;
}

// ---------------------------------------------------------------------------
// Output projection: Out(fp32) = AO(bf16) * Wo_bf^T, m97-style DMA staging.
// ---------------------------------------------------------------------------
__global__ __launch_bounds__(256) void out_proj_kernel(
    const u16* __restrict__ A, const u16* __restrict__ Wob, float* __restrict__ Out)
{
    __shared__ __align__(16) u16 smem[16384];
    u16* As = smem;
    u16* Bs = smem + 8192;

    const int tid = threadIdx.x;
    const int m0 = blockIdx.y * 128;
    const int n0 = blockIdx.x * 128;

    const int w = tid >> 6, L = tid & 63, quad = L >> 4, colL = L & 15;
    const int mw = (w & 1) * 64, nw = (w >> 1) * 64;

    const int lrow = L >> 3;
    const int lchk = (L & 7) ^ lrow;
    const u16* ag = A + (size_t)(m0 + 32 * w + lrow) * D_MODEL + lchk * 8;
    const u16* bg = Wob + (size_t)(n0 + 32 * w + lrow) * D_MODEL + lchk * 8;
    u16* al = As + (32 * w) * 64;
    u16* bl = Bs + (32 * w) * 64;

    f32x4_t acc[4][4];
    #pragma unroll
    for (int i = 0; i < 4; ++i)
        #pragma unroll
        for (int j = 0; j < 4; ++j) acc[i][j] = (f32x4_t){0.f, 0.f, 0.f, 0.f};

    for (int k0 = 0; k0 < D_MODEL; k0 += 64) {
        __syncthreads();
        #pragma unroll
        for (int j = 0; j < 4; ++j) {
            dma16(ag + (size_t)j * 8 * D_MODEL + k0, al + j * 512);
            dma16(bg + (size_t)j * 8 * D_MODEL + k0, bl + j * 512);
        }
        __syncthreads();
        #pragma unroll
        for (int kb = 0; kb < 2; ++kb) {
            const int ch = ((kb * 4 + quad) ^ (colL & 7)) * 8;
            bf16x8_t af[4], bf[4];
            #pragma unroll
            for (int t = 0; t < 4; ++t) {
                af[t] = frag_ld(As + (mw + t * 16 + colL) * 64 + ch);
                bf[t] = frag_ld(Bs + (nw + t * 16 + colL) * 64 + ch);
            }
            #pragma unroll
            for (int mt = 0; mt < 4; ++mt)
                #pragma unroll
                for (int nt = 0; nt < 4; ++nt)
                    acc[mt][nt] = __builtin_amdgcn_mfma_f32_16x16x32_bf16(
                        af[mt], bf[nt], acc[mt][nt], 0, 0, 0);
        }
    }

    #pragma unroll
    for (int mt = 0; mt < 4; ++mt)
        #pragma unroll
        for (int nt = 0; nt < 4; ++nt)
            #pragma unroll
            for (int r = 0; r < 4; ++r) {
                const int m = m0 + mw + mt * 16 + quad * 4 + r;
                const int n = n0 + nw + nt * 16 + colL;
                Out[(size_t)m * D_MODEL + n] = acc[mt][nt][r];
            }
}

// ---------------------------------------------------------------------------
extern "C" void kernel_launch(void* const* d_in, const int* in_sizes, int n_in,
                              void* d_out, int out_size, void* d_ws, size_t ws_size,
                              hipStream_t stream) {
    const float* x  = (const float*)d_in[0];
    const float* wq = (const float*)d_in[1];
    const float* wk = (const float*)d_in[2];
    const float* wv = (const float*)d_in[3];
    const float* wo = (const float*)d_in[4];
    const int* pos  = (const int*)d_in[5];
    float* out = (float*)d_out;

    const size_t NELEM = (size_t)BATCH * NHEADS * SEQ * HDIM;  // 4,194,304
    u16* Qw  = (u16*)d_ws;
    u16* Kw  = Qw + NELEM;
    u16* Vtw = Kw + NELEM;
    u16* AOw = Vtw + NELEM;        // doubles as Xbf (attn writes after qkv reads)
    u16* Xbf = AOw;
    u16* Wbf = AOw + NELEM;        // 4M elems (wq|wk|wv|wo)
    u16* Opart = Wbf + NELEM;      // 2560 slots x 4096 u16 = 21MB
    float* Lpart = (float*)(Opart + (size_t)2560 * 4096);  // 2560 x 64 fp32

    conv_bf16_kernel<<<4096, 256, 0, stream>>>(x, wq, wk, wv, wo, Xbf, Wbf);
    qkv_rope_kernel<<<dim3(24, 32), 256, 0, stream>>>(Xbf, Wbf, pos, Qw, Kw, Vtw);
    attn_kernel<<<dim3(80, NHEADS, BATCH), 256, 0, stream>>>(Qw, Kw, Vtw, Opart, Lpart);
    combine_kernel<<<dim3(32, NHEADS, BATCH), 256, 0, stream>>>(Opart, Lpart, AOw);
    out_proj_kernel<<<dim3(8, 32), 256, 0, stream>>>(AOw, Wbf + 3 * (1u << 20), out);
}